// Round 1
// baseline (3604.116 us; speedup 1.0000x reference)
//
#include <hip/hip_runtime.h>
#include <cmath>

constexpr int BB = 4;
constexpr int SS = 8192;
constexpr int DMODEL = 1024;
constexpr int NHEADS = 16;
constexpr int DHEAD = 64;
constexpr int MTOK = BB * SS; // 32768

// ---------------------------------------------------------------------------
// Tiled fp32 GEMM: C = A(MxK) x B(KxN), row-major. 128x128 tile, BK=8,
// 256 threads, 8x8 microtile per thread.
// EPI==1: split N=3072 output into q/k/v buffers (each ld=1024), apply
//         elu(x)+1  (== x>0 ? x+1 : exp(x)) to q and k columns.
// EPI==0: plain store to C0 with ld = N.
// ---------------------------------------------------------------------------
template <int EPI>
__global__ __launch_bounds__(256) void la_sgemm(
    const float* __restrict__ A, const float* __restrict__ Bm,
    float* __restrict__ C0, float* __restrict__ C1, float* __restrict__ C2,
    int M, int N, int K)
{
    __shared__ float As[8][128];   // transposed A tile: As[k][m]
    __shared__ float Bs[8][128];   // Bs[k][n]
    const int t = threadIdx.x;
    const int m0 = blockIdx.y * 128;
    const int n0 = blockIdx.x * 128;
    const int tx = t & 15, ty = t >> 4;
    const int row0 = ty * 8, col0 = tx * 8;

    // staging assignments
    const int aRow = t >> 1, aCol = (t & 1) * 4;   // 128 rows x 8 cols, float4
    const int bRow = t >> 5, bCol = (t & 31) * 4;  // 8 rows x 128 cols, float4

    const float* ap = A + (size_t)(m0 + aRow) * K + aCol;
    const float* bp = Bm + (size_t)bRow * N + (n0 + bCol);

    float acc[8][8];
#pragma unroll
    for (int i = 0; i < 8; ++i)
#pragma unroll
        for (int j = 0; j < 8; ++j) acc[i][j] = 0.f;

    const int ktiles = K >> 3;
    for (int kt = 0; kt < ktiles; ++kt) {
        float4 av = *(const float4*)ap;
        float4 bv = *(const float4*)bp;
        __syncthreads();
        As[aCol + 0][aRow] = av.x;
        As[aCol + 1][aRow] = av.y;
        As[aCol + 2][aRow] = av.z;
        As[aCol + 3][aRow] = av.w;
        *(float4*)&Bs[bRow][bCol] = bv;
        __syncthreads();
#pragma unroll
        for (int kk = 0; kk < 8; ++kk) {
            float4 a0 = *(const float4*)&As[kk][row0];
            float4 a1 = *(const float4*)&As[kk][row0 + 4];
            float4 b0 = *(const float4*)&Bs[kk][col0];
            float4 b1 = *(const float4*)&Bs[kk][col0 + 4];
            float a[8] = {a0.x, a0.y, a0.z, a0.w, a1.x, a1.y, a1.z, a1.w};
            float b[8] = {b0.x, b0.y, b0.z, b0.w, b1.x, b1.y, b1.z, b1.w};
#pragma unroll
            for (int i = 0; i < 8; ++i)
#pragma unroll
                for (int j = 0; j < 8; ++j)
                    acc[i][j] = fmaf(a[i], b[j], acc[i][j]);
        }
        ap += 8;
        bp += (size_t)8 * N;
    }

    if (EPI == 1) {
        // whole block lies in one of q/k/v (1024 % 128 == 0)
        const int bsel = n0 >> 10;
        const int cb = (n0 & 1023) + col0;
        float* Cp = (bsel == 0) ? C0 : ((bsel == 1) ? C1 : C2);
        const bool act = (bsel < 2);
#pragma unroll
        for (int i = 0; i < 8; ++i) {
            float v[8];
#pragma unroll
            for (int j = 0; j < 8; ++j) {
                float xv = acc[i][j];
                v[j] = act ? (xv > 0.f ? xv + 1.f : __expf(xv)) : xv;
            }
            float* o = Cp + (size_t)(m0 + row0 + i) * 1024 + cb;
            *(float4*)o       = make_float4(v[0], v[1], v[2], v[3]);
            *(float4*)(o + 4) = make_float4(v[4], v[5], v[6], v[7]);
        }
    } else {
#pragma unroll
        for (int i = 0; i < 8; ++i) {
            float* o = C0 + (size_t)(m0 + row0 + i) * N + n0 + col0;
            *(float4*)o       = make_float4(acc[i][0], acc[i][1], acc[i][2], acc[i][3]);
            *(float4*)(o + 4) = make_float4(acc[i][4], acc[i][5], acc[i][6], acc[i][7]);
        }
    }
}

// ---------------------------------------------------------------------------
// kv[b,h,d,f] = sum_s k[b,s,h,d] * v[b,s,h,f];  ksum[b,h,d] = sum_s k.
// grid = (B*H, CHUNKS). Each block reduces S/CHUNKS rows, atomicAdd at end.
// ---------------------------------------------------------------------------
constexpr int KV_CHUNKS = 16;

__global__ __launch_bounds__(256) void la_kvsum(
    const float* __restrict__ Kb, const float* __restrict__ Vb,
    float* __restrict__ kv, float* __restrict__ ksum)
{
    __shared__ float kk[32][68];  // +4 pad to spread banks
    __shared__ float vv[32][68];
    const int t = threadIdx.x;
    const int bh = blockIdx.x;
    const int b = bh >> 4, h = bh & 15;
    const int r = t >> 3, c8 = (t & 7) * 8;       // staging: 32 rows x 64 cols
    const int d0 = (t & 15) * 4, f0 = (t >> 4) * 4;  // compute: 4x4 cells
    float acc[4][4];
#pragma unroll
    for (int i = 0; i < 4; ++i)
#pragma unroll
        for (int j = 0; j < 4; ++j) acc[i][j] = 0.f;
    float ks = 0.f;
    const int s0 = blockIdx.y * (SS / KV_CHUNKS);

    for (int st = 0; st < SS / KV_CHUNKS; st += 32) {
        const size_t row = (size_t)(b * SS + s0 + st + r) * DMODEL + h * DHEAD + c8;
        float4 k0 = *(const float4*)(Kb + row);
        float4 k1 = *(const float4*)(Kb + row + 4);
        float4 v0 = *(const float4*)(Vb + row);
        float4 v1 = *(const float4*)(Vb + row + 4);
        __syncthreads();
        *(float4*)&kk[r][c8]     = k0;
        *(float4*)&kk[r][c8 + 4] = k1;
        *(float4*)&vv[r][c8]     = v0;
        *(float4*)&vv[r][c8 + 4] = v1;
        __syncthreads();
#pragma unroll 8
        for (int rr = 0; rr < 32; ++rr) {
            float4 kr = *(const float4*)&kk[rr][d0];
            float4 vr = *(const float4*)&vv[rr][f0];
            float ka[4] = {kr.x, kr.y, kr.z, kr.w};
            float va[4] = {vr.x, vr.y, vr.z, vr.w};
#pragma unroll
            for (int i = 0; i < 4; ++i)
#pragma unroll
                for (int j = 0; j < 4; ++j)
                    acc[i][j] = fmaf(ka[i], va[j], acc[i][j]);
        }
        if (t < 64) {
#pragma unroll 8
            for (int rr = 0; rr < 32; ++rr) ks += kk[rr][t];
        }
    }

    float* kvp = kv + (size_t)bh * DHEAD * DHEAD;
#pragma unroll
    for (int i = 0; i < 4; ++i)
#pragma unroll
        for (int j = 0; j < 4; ++j)
            atomicAdd(&kvp[(d0 + i) * DHEAD + f0 + j], acc[i][j]);
    if (t < 64) atomicAdd(&ksum[bh * DHEAD + t], ks);
}

// ---------------------------------------------------------------------------
// attn[t, h*64+f] = (sum_d q[t,h,d]*kv[b,h,d,f]) / (sum_d q[t,h,d]*ksum[b,h,d] + 1e-6)
// One block = 4 tokens (one wave per token).
// ---------------------------------------------------------------------------
__global__ __launch_bounds__(256) void la_attn(
    const float* __restrict__ Q, const float* __restrict__ kv,
    const float* __restrict__ ksum, float* __restrict__ attn)
{
    __shared__ float qs[4 * DMODEL];
    const int t = threadIdx.x;
    const int tok0 = blockIdx.x * 4;
    const int b = tok0 / SS;  // SS % 4 == 0, all 4 tokens same batch
#pragma unroll
    for (int j = 0; j < 4; ++j)
        *(float4*)&qs[j * DMODEL + t * 4] =
            *(const float4*)(Q + (size_t)(tok0 + j) * DMODEL + t * 4);
    __syncthreads();
    const int lane = t & 63, tok = t >> 6;
    const size_t obase = (size_t)(tok0 + tok) * DMODEL;
    for (int h = 0; h < NHEADS; ++h) {
        const float* kvp = kv + (size_t)(b * NHEADS + h) * DHEAD * DHEAD;
        const float* ksp = ksum + (b * NHEADS + h) * DHEAD;
        const float* qp = &qs[tok * DMODEL + h * DHEAD];
        float num = 0.f, den = 0.f;
#pragma unroll 8
        for (int d = 0; d < DHEAD; ++d) {
            float qd = qp[d];
            num = fmaf(qd, kvp[d * DHEAD + lane], num);
            den = fmaf(qd, ksp[d], den);
        }
        attn[obase + h * DHEAD + lane] = num / (den + 1e-6f);
    }
}

// ---------------------------------------------------------------------------
extern "C" void kernel_launch(void* const* d_in, const int* in_sizes, int n_in,
                              void* d_out, int out_size, void* d_ws, size_t ws_size,
                              hipStream_t stream)
{
    const float* x     = (const float*)d_in[0];  // (B,S,1024)
    const float* w_qkv = (const float*)d_in[1];  // (1024,3072)
    const float* w_o   = (const float*)d_in[2];  // (1024,1024)
    float* out = (float*)d_out;                  // (B,S,1024) fp32

    // workspace layout
    const size_t n_tok_dm = (size_t)MTOK * DMODEL;            // 33.5M floats
    float* q_buf = (float*)d_ws;
    float* k_buf = q_buf + n_tok_dm;
    float* v_buf = k_buf + n_tok_dm;                          // attn reuses k_buf
    float* kv    = v_buf + n_tok_dm;                          // 64*4096 floats
    float* ksum  = kv + (size_t)BB * NHEADS * DHEAD * DHEAD;  // 1024 floats

    const size_t need = (3 * n_tok_dm +
                         (size_t)BB * NHEADS * DHEAD * DHEAD +
                         (size_t)BB * NHEADS * DHEAD) * sizeof(float);
    if (ws_size < need) return;  // workspace too small — will fail visibly

    // zero kv/ksum (they are atomically accumulated)
    hipMemsetAsync(kv, 0,
                   (size_t)(BB * NHEADS * DHEAD * DHEAD + BB * NHEADS * DHEAD) * sizeof(float),
                   stream);

    // 1) qkv = x @ w_qkv, fused elu+1 on q,k; split into q/k/v buffers
    {
        dim3 grid(3 * DMODEL / 128, MTOK / 128);
        la_sgemm<1><<<grid, 256, 0, stream>>>(x, w_qkv, q_buf, k_buf, v_buf,
                                              MTOK, 3 * DMODEL, DMODEL);
    }
    // 2) kv = k^T v, ksum = sum k   (per b,h)
    {
        dim3 grid(BB * NHEADS, KV_CHUNKS);
        la_kvsum<<<grid, 256, 0, stream>>>(k_buf, v_buf, kv, ksum);
    }
    // 3) attn = (q . kv) / (q . ksum + 1e-6)  -> overwrite k_buf
    la_attn<<<MTOK / 4, 256, 0, stream>>>(q_buf, kv, ksum, k_buf);

    // 4) out = attn @ w_o
    {
        dim3 grid(DMODEL / 128, MTOK / 128);
        la_sgemm<0><<<grid, 256, 0, stream>>>(k_buf, w_o, out, nullptr, nullptr,
                                              MTOK, DMODEL, DMODEL);
    }
}

// Round 3
// 1407.795 us; speedup vs baseline: 2.5601x; 2.5601x over previous
//
#include <hip/hip_runtime.h>
#include <cmath>

constexpr int BB = 4;
constexpr int SS = 8192;
constexpr int DMODEL = 1024;
constexpr int NHEADS = 16;
constexpr int DHEAD = 64;
constexpr int MTOK = BB * SS; // 32768

typedef __attribute__((ext_vector_type(8))) short short8; // 8 bf16 in 4 VGPRs
typedef __attribute__((ext_vector_type(4))) float f32x4;

__device__ __forceinline__ unsigned short f2bf(float f) {
    unsigned u = __float_as_uint(f);
    u += 0x7FFF + ((u >> 16) & 1); // RNE
    return (unsigned short)(u >> 16);
}
__device__ __forceinline__ float bf2f(unsigned short h) {
    return __uint_as_float(((unsigned)h) << 16);
}

// ---------------------------------------------------------------------------
// Stage a 128x32 bf16 tile (row-major, ld elements) into LDS via
// global_load_lds 16B/lane. XOR swizzle on 16B chunk index: LDS chunk (r,q)
// holds global chunk (r, q ^ ((r>>1)&3)) -> frag ds_read_b128s are <=2-way
// bank aliased (free, m136).
// ---------------------------------------------------------------------------
__device__ __forceinline__ void stage_tile(const unsigned short* g0, int ld,
                                           unsigned short* lds, int wave, int lane) {
#pragma unroll
    for (int i = 0; i < 2; ++i) {
        const int c = (wave * 2 + i) * 64 + lane;   // chunk 0..511
        const int r = c >> 2;                       // tile row 0..127
        const int qg = (c & 3) ^ ((r >> 1) & 3);    // swizzled source chunk
        const unsigned short* g = g0 + (size_t)r * ld + qg * 8;
        unsigned short* l = lds + (wave * 2 + i) * 512; // wave-uniform base
        __builtin_amdgcn_global_load_lds(
            (const __attribute__((address_space(1))) unsigned int*)g,
            (__attribute__((address_space(3))) unsigned int*)l, 16, 0, 0);
    }
}

// fragment = 8 bf16 along k at row r, k-chunk q (0..3), undoing the swizzle
__device__ __forceinline__ short8 frag_ld(const unsigned short* lds, int r, int q) {
    const int qs = q ^ ((r >> 1) & 3);
    return *(const short8*)(lds + r * 32 + qs * 8);
}

// ---------------------------------------------------------------------------
// bf16x3 split MFMA GEMM: C = (Ah+Al)(Bh+Bl) ~= AhBh + AhBl + AlBh.
// A: M x K row-major hi/lo bf16. B: N x K row-major hi/lo (pre-transposed).
// 128x128 tile, BK=32, 4 waves 2x2, each wave 64x64 via 4x4 16x16x32 MFMAs.
// EPI==1: N=3072 -> q/k/v as BF16 (ld 1024), elu+1 fused on q,k.
// EPI==0: plain fp32 store to Cf (ld N).
// ---------------------------------------------------------------------------
template <int EPI>
__global__ __launch_bounds__(256) void la_mfma_gemm(
    const unsigned short* __restrict__ Ah, const unsigned short* __restrict__ Al,
    const unsigned short* __restrict__ Bh, const unsigned short* __restrict__ Bl,
    float* __restrict__ Cf,
    unsigned short* __restrict__ Cq, unsigned short* __restrict__ Ck,
    unsigned short* __restrict__ Cv,
    int N, int K)
{
    __shared__ __align__(16) unsigned short smem[4 * 4096]; // 32 KB
    unsigned short* sAh = smem;
    unsigned short* sAl = smem + 4096;
    unsigned short* sBh = smem + 8192;
    unsigned short* sBl = smem + 12288;

    const int t = threadIdx.x;
    const int wave = t >> 6, lane = t & 63;
    const int wm = wave & 1, wn = wave >> 1;
    const int quad = lane >> 4, fl = lane & 15;
    const int m0 = blockIdx.y * 128, n0 = blockIdx.x * 128;

    const unsigned short* a_h = Ah + (size_t)m0 * K;
    const unsigned short* a_l = Al + (size_t)m0 * K;
    const unsigned short* b_h = Bh + (size_t)n0 * K;
    const unsigned short* b_l = Bl + (size_t)n0 * K;

    f32x4 acc[4][4];
#pragma unroll
    for (int i = 0; i < 4; ++i)
#pragma unroll
        for (int j = 0; j < 4; ++j) acc[i][j] = (f32x4){0.f, 0.f, 0.f, 0.f};

    for (int kt = 0; kt < K; kt += 32) {
        __syncthreads(); // prev iter's ds_reads done before overwrite
        stage_tile(a_h + kt, K, sAh, wave, lane);
        stage_tile(a_l + kt, K, sAl, wave, lane);
        stage_tile(b_h + kt, K, sBh, wave, lane);
        stage_tile(b_l + kt, K, sBl, wave, lane);
        __syncthreads(); // vmcnt drained: staged data visible

        short8 ah[4], al[4], bh[4], bl[4];
#pragma unroll
        for (int i = 0; i < 4; ++i) {
            const int ra = wm * 64 + i * 16 + fl;
            ah[i] = frag_ld(sAh, ra, quad);
            al[i] = frag_ld(sAl, ra, quad);
            const int rb = wn * 64 + i * 16 + fl;
            bh[i] = frag_ld(sBh, rb, quad);
            bl[i] = frag_ld(sBl, rb, quad);
        }
#pragma unroll
        for (int i = 0; i < 4; ++i)
#pragma unroll
            for (int j = 0; j < 4; ++j) {
                acc[i][j] = __builtin_amdgcn_mfma_f32_16x16x32_bf16(ah[i], bh[j], acc[i][j], 0, 0, 0);
                acc[i][j] = __builtin_amdgcn_mfma_f32_16x16x32_bf16(ah[i], bl[j], acc[i][j], 0, 0, 0);
                acc[i][j] = __builtin_amdgcn_mfma_f32_16x16x32_bf16(al[i], bh[j], acc[i][j], 0, 0, 0);
            }
    }

    // C/D layout (m89-verified): col = lane&15, row = (lane>>4)*4 + reg
    if (EPI == 1) {
        const int bsel = n0 >> 10; // 0:q 1:k 2:v
        unsigned short* Cp = (bsel == 0) ? Cq : ((bsel == 1) ? Ck : Cv);
        const bool act = (bsel < 2);
        const int colb = (n0 & 1023) + wn * 64 + fl;
#pragma unroll
        for (int i = 0; i < 4; ++i) {
            const int rowb = m0 + wm * 64 + i * 16 + quad * 4;
#pragma unroll
            for (int j = 0; j < 4; ++j) {
                const int col = colb + j * 16;
#pragma unroll
                for (int r = 0; r < 4; ++r) {
                    float v = acc[i][j][r];
                    if (act) v = (v > 0.f) ? v + 1.f : __expf(v);
                    Cp[(size_t)(rowb + r) * 1024 + col] = f2bf(v);
                }
            }
        }
    } else {
#pragma unroll
        for (int i = 0; i < 4; ++i) {
            const int rowb = m0 + wm * 64 + i * 16 + quad * 4;
#pragma unroll
            for (int j = 0; j < 4; ++j) {
                const int col = n0 + wn * 64 + fl + j * 16;
#pragma unroll
                for (int r = 0; r < 4; ++r)
                    Cf[(size_t)(rowb + r) * N + col] = acc[i][j][r];
            }
        }
    }
}

// ---------------------------------------------------------------------------
// fp32 -> bf16 hi/lo split, elementwise (for x)
// ---------------------------------------------------------------------------
__global__ __launch_bounds__(256) void split_plain(
    const float4* __restrict__ in, ushort4* __restrict__ hi, ushort4* __restrict__ lo, int n4)
{
    int i = blockIdx.x * 256 + threadIdx.x;
    const int stride = gridDim.x * 256;
    for (; i < n4; i += stride) {
        const float4 v = in[i];
        ushort4 h, l;
        h.x = f2bf(v.x); l.x = f2bf(v.x - bf2f(h.x));
        h.y = f2bf(v.y); l.y = f2bf(v.y - bf2f(h.y));
        h.z = f2bf(v.z); l.z = f2bf(v.z - bf2f(h.z));
        h.w = f2bf(v.w); l.w = f2bf(v.w - bf2f(h.w));
        hi[i] = h; lo[i] = l;
    }
}

// ---------------------------------------------------------------------------
// fp32 K x N -> bf16 hi/lo N x K (transposed split, for weights)
// ---------------------------------------------------------------------------
__global__ __launch_bounds__(256) void split_T(
    const float* __restrict__ w, unsigned short* __restrict__ hiT,
    unsigned short* __restrict__ loT, int Kd, int Nd)
{
    __shared__ float tile[32][33];
    const int t = threadIdx.x;
    const int n0 = blockIdx.x * 32, k0 = blockIdx.y * 32;
    const int r = t >> 3, c4 = (t & 7) * 4;
    const float4 v = *(const float4*)(w + (size_t)(k0 + r) * Nd + n0 + c4);
    tile[r][c4 + 0] = v.x; tile[r][c4 + 1] = v.y;
    tile[r][c4 + 2] = v.z; tile[r][c4 + 3] = v.w;
    __syncthreads();
    const float a0 = tile[c4 + 0][r], a1 = tile[c4 + 1][r];
    const float a2 = tile[c4 + 2][r], a3 = tile[c4 + 3][r];
    ushort4 h, l;
    h.x = f2bf(a0); l.x = f2bf(a0 - bf2f(h.x));
    h.y = f2bf(a1); l.y = f2bf(a1 - bf2f(h.y));
    h.z = f2bf(a2); l.z = f2bf(a2 - bf2f(h.z));
    h.w = f2bf(a3); l.w = f2bf(a3 - bf2f(h.w));
    *(ushort4*)(hiT + (size_t)(n0 + r) * Kd + k0 + c4) = h;
    *(ushort4*)(loT + (size_t)(n0 + r) * Kd + k0 + c4) = l;
}

// ---------------------------------------------------------------------------
// kv[b,h,d,f] = sum_s k[s,d]*v[s,f];  ksum[b,h,d] = sum_s k.  (bf16 in, fp32 out)
// ---------------------------------------------------------------------------
constexpr int KV_CHUNKS = 16;

__global__ __launch_bounds__(256) void la_kvsum(
    const unsigned short* __restrict__ Kb, const unsigned short* __restrict__ Vb,
    float* __restrict__ kv, float* __restrict__ ksum)
{
    __shared__ float kk[32][68];
    __shared__ float vv[32][68];
    const int t = threadIdx.x;
    const int bh = blockIdx.x;
    const int b = bh >> 4, h = bh & 15;
    const int r = t >> 3, c8 = (t & 7) * 8;
    const int d0 = (t & 15) * 4, f0 = (t >> 4) * 4;
    float acc[4][4];
#pragma unroll
    for (int i = 0; i < 4; ++i)
#pragma unroll
        for (int j = 0; j < 4; ++j) acc[i][j] = 0.f;
    float ks = 0.f;
    const int s0 = blockIdx.y * (SS / KV_CHUNKS);

    for (int st = 0; st < SS / KV_CHUNKS; st += 32) {
        const size_t row = (size_t)(b * SS + s0 + st + r) * DMODEL + h * DHEAD + c8;
        const uint4 ku = *(const uint4*)(Kb + row);  // 8 bf16
        const uint4 vu = *(const uint4*)(Vb + row);
        __syncthreads();
        const unsigned ka_[4] = {ku.x, ku.y, ku.z, ku.w};
        const unsigned va_[4] = {vu.x, vu.y, vu.z, vu.w};
#pragma unroll
        for (int e = 0; e < 4; ++e) {
            kk[r][c8 + 2 * e]     = __uint_as_float(ka_[e] << 16);
            kk[r][c8 + 2 * e + 1] = __uint_as_float(ka_[e] & 0xFFFF0000u);
            vv[r][c8 + 2 * e]     = __uint_as_float(va_[e] << 16);
            vv[r][c8 + 2 * e + 1] = __uint_as_float(va_[e] & 0xFFFF0000u);
        }
        __syncthreads();
#pragma unroll 8
        for (int rr = 0; rr < 32; ++rr) {
            float4 kr = *(const float4*)&kk[rr][d0];
            float4 vr = *(const float4*)&vv[rr][f0];
            float ka[4] = {kr.x, kr.y, kr.z, kr.w};
            float va[4] = {vr.x, vr.y, vr.z, vr.w};
#pragma unroll
            for (int i = 0; i < 4; ++i)
#pragma unroll
                for (int j = 0; j < 4; ++j)
                    acc[i][j] = fmaf(ka[i], va[j], acc[i][j]);
        }
        if (t < 64) {
#pragma unroll 8
            for (int rr = 0; rr < 32; ++rr) ks += kk[rr][t];
        }
    }

    float* kvp = kv + (size_t)bh * DHEAD * DHEAD;
#pragma unroll
    for (int i = 0; i < 4; ++i)
#pragma unroll
        for (int j = 0; j < 4; ++j)
            atomicAdd(&kvp[(d0 + i) * DHEAD + f0 + j], acc[i][j]);
    if (t < 64) atomicAdd(&ksum[bh * DHEAD + t], ks);
}

// ---------------------------------------------------------------------------
// attn = (q.kv)/(q.ksum+1e-6); q is bf16; emit bf16 hi/lo for the w_o GEMM
// ---------------------------------------------------------------------------
__global__ __launch_bounds__(256) void la_attn(
    const unsigned short* __restrict__ Q, const float* __restrict__ kv,
    const float* __restrict__ ksum,
    unsigned short* __restrict__ Ahi, unsigned short* __restrict__ Alo)
{
    __shared__ float qs[4 * DMODEL];
    const int t = threadIdx.x;
    const int tok0 = blockIdx.x * 4;
    const int b = tok0 / SS;
#pragma unroll
    for (int j = 0; j < 4; ++j) {
        const uint2 qu = *(const uint2*)(Q + (size_t)(tok0 + j) * DMODEL + t * 4); // 4 bf16
        qs[j * DMODEL + t * 4 + 0] = __uint_as_float(qu.x << 16);
        qs[j * DMODEL + t * 4 + 1] = __uint_as_float(qu.x & 0xFFFF0000u);
        qs[j * DMODEL + t * 4 + 2] = __uint_as_float(qu.y << 16);
        qs[j * DMODEL + t * 4 + 3] = __uint_as_float(qu.y & 0xFFFF0000u);
    }
    __syncthreads();
    const int lane = t & 63, tok = t >> 6;
    const size_t obase = (size_t)(tok0 + tok) * DMODEL;
    for (int hh = 0; hh < NHEADS; ++hh) {
        const float* kvp = kv + (size_t)(b * NHEADS + hh) * DHEAD * DHEAD;
        const float* ksp = ksum + (b * NHEADS + hh) * DHEAD;
        const float* qp = &qs[tok * DMODEL + hh * DHEAD];
        float num = 0.f, den = 0.f;
#pragma unroll 8
        for (int d = 0; d < DHEAD; ++d) {
            float qd = qp[d];
            num = fmaf(qd, kvp[d * DHEAD + lane], num);
            den = fmaf(qd, ksp[d], den);
        }
        const float val = num / (den + 1e-6f);
        const unsigned short hb = f2bf(val);
        Ahi[obase + hh * DHEAD + lane] = hb;
        Alo[obase + hh * DHEAD + lane] = f2bf(val - bf2f(hb));
    }
}

// sentinel: unmistakable marker if workspace is too small
__global__ void la_sentinel(float* out, int n) {
    int i = blockIdx.x * 256 + threadIdx.x;
    if (i < n) out[i] = 12345.0f;
}

// ---------------------------------------------------------------------------
extern "C" void kernel_launch(void* const* d_in, const int* in_sizes, int n_in,
                              void* d_out, int out_size, void* d_ws, size_t ws_size,
                              hipStream_t stream)
{
    const float* x     = (const float*)d_in[0];  // (B,S,1024)
    const float* w_qkv = (const float*)d_in[1];  // (1024,3072)
    const float* w_o   = (const float*)d_in[2];  // (1024,1024)
    float* out = (float*)d_out;

    // workspace layout (bytes) — total ~353 MB (< 385 MB proven available)
    char* p = (char*)d_ws;
    const size_t x_bf = (size_t)MTOK * DMODEL * 2;          // 67.1 MB each
    unsigned short* x_hi = (unsigned short*)p; p += x_bf;   // reused as attn_hi
    unsigned short* x_lo = (unsigned short*)p; p += x_bf;   // reused as attn_lo
    unsigned short* wqT_hi = (unsigned short*)p; p += (size_t)3 * DMODEL * DMODEL * 2;
    unsigned short* wqT_lo = (unsigned short*)p; p += (size_t)3 * DMODEL * DMODEL * 2;
    unsigned short* woT_hi = (unsigned short*)p; p += (size_t)DMODEL * DMODEL * 2;
    unsigned short* woT_lo = (unsigned short*)p; p += (size_t)DMODEL * DMODEL * 2;
    unsigned short* q_buf = (unsigned short*)p; p += x_bf;  // bf16 q/k/v
    unsigned short* k_buf = (unsigned short*)p; p += x_bf;
    unsigned short* v_buf = (unsigned short*)p; p += x_bf;
    float* kvb = (float*)p; p += (size_t)BB * NHEADS * DHEAD * DHEAD * 4;
    float* ksb = (float*)p; p += (size_t)BB * NHEADS * DHEAD * 4;

    if ((size_t)(p - (char*)d_ws) > ws_size) {
        la_sentinel<<<(MTOK * DMODEL + 255) / 256, 256, 0, stream>>>(out, MTOK * DMODEL);
        return;
    }

    hipMemsetAsync(kvb, 0,
                   (size_t)(BB * NHEADS * DHEAD * DHEAD + BB * NHEADS * DHEAD) * sizeof(float),
                   stream);

    // 0) precision splits
    split_plain<<<8192, 256, 0, stream>>>((const float4*)x, (ushort4*)x_hi, (ushort4*)x_lo,
                                          MTOK * DMODEL / 4);
    split_T<<<dim3(3 * DMODEL / 32, DMODEL / 32), 256, 0, stream>>>(w_qkv, wqT_hi, wqT_lo,
                                                                    DMODEL, 3 * DMODEL);
    split_T<<<dim3(DMODEL / 32, DMODEL / 32), 256, 0, stream>>>(w_o, woT_hi, woT_lo,
                                                                DMODEL, DMODEL);

    // 1) qkv GEMM (elu+1 fused on q,k), bf16 outputs
    la_mfma_gemm<1><<<dim3(3 * DMODEL / 128, MTOK / 128), 256, 0, stream>>>(
        x_hi, x_lo, wqT_hi, wqT_lo, nullptr, q_buf, k_buf, v_buf, 3 * DMODEL, DMODEL);

    // 2) kv / ksum reduction (bf16 in, fp32 out)
    la_kvsum<<<dim3(BB * NHEADS, KV_CHUNKS), 256, 0, stream>>>(k_buf, v_buf, kvb, ksb);

    // 3) attn -> bf16 hi/lo (reuses x_hi/x_lo; x is dead)
    la_attn<<<MTOK / 4, 256, 0, stream>>>(q_buf, kvb, ksb, x_hi, x_lo);

    // 4) out = attn @ w_o (fp32 out)
    la_mfma_gemm<0><<<dim3(DMODEL / 128, MTOK / 128), 256, 0, stream>>>(
        x_hi, x_lo, woT_hi, woT_lo, out, nullptr, nullptr, nullptr, DMODEL, DMODEL);
}

// Round 4
// 825.591 us; speedup vs baseline: 4.3655x; 1.7052x over previous
//
#include <hip/hip_runtime.h>
#include <cmath>

constexpr int BB = 4;
constexpr int SS = 8192;
constexpr int DMODEL = 1024;
constexpr int NHEADS = 16;
constexpr int DHEAD = 64;
constexpr int MTOK = BB * SS; // 32768

typedef __attribute__((ext_vector_type(8))) short short8; // 8 bf16 in 4 VGPRs
typedef __attribute__((ext_vector_type(4))) float f32x4;

__device__ __forceinline__ unsigned short f2bf(float f) {
    unsigned u = __float_as_uint(f);
    u += 0x7FFF + ((u >> 16) & 1); // RNE
    return (unsigned short)(u >> 16);
}
__device__ __forceinline__ float bf2f(unsigned short h) {
    return __uint_as_float(((unsigned)h) << 16);
}

// ---------------------------------------------------------------------------
// Stage a 128x64 bf16 tile (row-major, ld elements) into LDS via
// global_load_lds 16B/lane. Row = 8 chunks of 16B. XOR swizzle: LDS chunk
// (r, qL) holds global chunk (r, qL ^ (r&7)) -> each 8-lane phase of a
// ds_read_b128 hits 8 distinct chunk columns (conflict-free; the BK=32
// variant of this measured SQ_LDS_BANK_CONFLICT == 0 in round 3).
// ---------------------------------------------------------------------------
__device__ __forceinline__ void stage_tile64(const unsigned short* g0, int ld,
                                             unsigned short* lds, int wave, int lane) {
#pragma unroll
    for (int i = 0; i < 4; ++i) {
        const int c = (wave * 4 + i) * 64 + lane;   // chunk 0..1023
        const int r = c >> 3;                       // tile row 0..127
        const int qg = (c & 7) ^ (r & 7);           // swizzled source chunk
        const unsigned short* g = g0 + (size_t)r * ld + qg * 8;
        unsigned short* l = lds + (wave * 4 + i) * 512; // wave-uniform base
        __builtin_amdgcn_global_load_lds(
            (const __attribute__((address_space(1))) unsigned int*)g,
            (__attribute__((address_space(3))) unsigned int*)l, 16, 0, 0);
    }
}

// fragment = 8 bf16 along k at row r, k-chunk q (0..7), undoing the swizzle
__device__ __forceinline__ short8 frag_ld64(const unsigned short* lds, int r, int q) {
    const int qs = q ^ (r & 7);
    return *(const short8*)(lds + r * 64 + qs * 8);
}

// ---------------------------------------------------------------------------
// Plain-bf16 MFMA GEMM: C = A x B^T. A: M x K row-major bf16. B: N x K
// row-major bf16 (pre-transposed). 128x128 tile, BK=64, 4 waves 2x2,
// each wave 64x64 via 4x4 16x16x32 MFMAs (32 MFMA per K-iter per wave).
// EPI==1: N=3072 -> q/k/v as bf16 (ld 1024), elu+1 fused on q,k.
// EPI==0: plain fp32 store to Cf (ld N).
// ---------------------------------------------------------------------------
template <int EPI>
__global__ __launch_bounds__(256) void la_gemm(
    const unsigned short* __restrict__ A, const unsigned short* __restrict__ B,
    float* __restrict__ Cf,
    unsigned short* __restrict__ Cq, unsigned short* __restrict__ Ck,
    unsigned short* __restrict__ Cv,
    int N, int K)
{
    __shared__ __align__(16) unsigned short smem[2 * 8192]; // 32 KB
    unsigned short* sA = smem;
    unsigned short* sB = smem + 8192;

    const int t = threadIdx.x;
    const int wave = t >> 6, lane = t & 63;
    const int wm = wave & 1, wn = wave >> 1;
    const int quad = lane >> 4, fl = lane & 15;
    const int m0 = blockIdx.y * 128, n0 = blockIdx.x * 128;

    const unsigned short* a_g = A + (size_t)m0 * K;
    const unsigned short* b_g = B + (size_t)n0 * K;

    f32x4 acc[4][4];
#pragma unroll
    for (int i = 0; i < 4; ++i)
#pragma unroll
        for (int j = 0; j < 4; ++j) acc[i][j] = (f32x4){0.f, 0.f, 0.f, 0.f};

    for (int kt = 0; kt < K; kt += 64) {
        __syncthreads(); // prev iter's ds_reads done before overwrite
        stage_tile64(a_g + kt, K, sA, wave, lane);
        stage_tile64(b_g + kt, K, sB, wave, lane);
        __syncthreads(); // vmcnt drained: staged data visible

        short8 ah[4][2], bh[4][2];
#pragma unroll
        for (int i = 0; i < 4; ++i) {
            const int ra = wm * 64 + i * 16 + fl;
            const int rb = wn * 64 + i * 16 + fl;
#pragma unroll
            for (int s = 0; s < 2; ++s) {
                ah[i][s] = frag_ld64(sA, ra, s * 4 + quad);
                bh[i][s] = frag_ld64(sB, rb, s * 4 + quad);
            }
        }
#pragma unroll
        for (int s = 0; s < 2; ++s)
#pragma unroll
            for (int i = 0; i < 4; ++i)
#pragma unroll
                for (int j = 0; j < 4; ++j)
                    acc[i][j] = __builtin_amdgcn_mfma_f32_16x16x32_bf16(
                        ah[i][s], bh[j][s], acc[i][j], 0, 0, 0);
    }

    // C/D layout (m89-verified): col = lane&15, row = (lane>>4)*4 + reg
    if (EPI == 1) {
        const int bsel = n0 >> 10; // 0:q 1:k 2:v
        unsigned short* Cp = (bsel == 0) ? Cq : ((bsel == 1) ? Ck : Cv);
        const bool act = (bsel < 2);
        const int colb = (n0 & 1023) + wn * 64 + fl;
#pragma unroll
        for (int i = 0; i < 4; ++i) {
            const int rowb = m0 + wm * 64 + i * 16 + quad * 4;
#pragma unroll
            for (int j = 0; j < 4; ++j) {
                const int col = colb + j * 16;
#pragma unroll
                for (int r = 0; r < 4; ++r) {
                    float v = acc[i][j][r];
                    if (act) v = (v > 0.f) ? v + 1.f : __expf(v);
                    Cp[(size_t)(rowb + r) * 1024 + col] = f2bf(v);
                }
            }
        }
    } else {
#pragma unroll
        for (int i = 0; i < 4; ++i) {
            const int rowb = m0 + wm * 64 + i * 16 + quad * 4;
#pragma unroll
            for (int j = 0; j < 4; ++j) {
                const int col = n0 + wn * 64 + fl + j * 16;
#pragma unroll
                for (int r = 0; r < 4; ++r)
                    Cf[(size_t)(rowb + r) * N + col] = acc[i][j][r];
            }
        }
    }
}

// ---------------------------------------------------------------------------
// fp32 -> bf16 cast, elementwise (for x)
// ---------------------------------------------------------------------------
__global__ __launch_bounds__(256) void cast_bf16(
    const float4* __restrict__ in, ushort4* __restrict__ hi, int n4)
{
    int i = blockIdx.x * 256 + threadIdx.x;
    const int stride = gridDim.x * 256;
    for (; i < n4; i += stride) {
        const float4 v = in[i];
        ushort4 h;
        h.x = f2bf(v.x); h.y = f2bf(v.y); h.z = f2bf(v.z); h.w = f2bf(v.w);
        hi[i] = h;
    }
}

// ---------------------------------------------------------------------------
// fp32 K x N -> bf16 N x K (transposed cast, for weights)
// ---------------------------------------------------------------------------
__global__ __launch_bounds__(256) void cast_T(
    const float* __restrict__ w, unsigned short* __restrict__ hiT, int Kd, int Nd)
{
    __shared__ float tile[32][33];
    const int t = threadIdx.x;
    const int n0 = blockIdx.x * 32, k0 = blockIdx.y * 32;
    const int r = t >> 3, c4 = (t & 7) * 4;
    const float4 v = *(const float4*)(w + (size_t)(k0 + r) * Nd + n0 + c4);
    tile[r][c4 + 0] = v.x; tile[r][c4 + 1] = v.y;
    tile[r][c4 + 2] = v.z; tile[r][c4 + 3] = v.w;
    __syncthreads();
    ushort4 h;
    h.x = f2bf(tile[c4 + 0][r]); h.y = f2bf(tile[c4 + 1][r]);
    h.z = f2bf(tile[c4 + 2][r]); h.w = f2bf(tile[c4 + 3][r]);
    *(ushort4*)(hiT + (size_t)(n0 + r) * Kd + k0 + c4) = h;
}

// ---------------------------------------------------------------------------
// kv[b,h,d,f] = sum_s k[s,d]*v[s,f];  ksum[b,h,d] = sum_s k.  (bf16 in, fp32 out)
// ---------------------------------------------------------------------------
constexpr int KV_CHUNKS = 16;

__global__ __launch_bounds__(256) void la_kvsum(
    const unsigned short* __restrict__ Kb, const unsigned short* __restrict__ Vb,
    float* __restrict__ kv, float* __restrict__ ksum)
{
    __shared__ float kk[32][68];
    __shared__ float vv[32][68];
    const int t = threadIdx.x;
    const int bh = blockIdx.x;
    const int b = bh >> 4, h = bh & 15;
    const int r = t >> 3, c8 = (t & 7) * 8;
    const int d0 = (t & 15) * 4, f0 = (t >> 4) * 4;
    float acc[4][4];
#pragma unroll
    for (int i = 0; i < 4; ++i)
#pragma unroll
        for (int j = 0; j < 4; ++j) acc[i][j] = 0.f;
    float ks = 0.f;
    const int s0 = blockIdx.y * (SS / KV_CHUNKS);

    for (int st = 0; st < SS / KV_CHUNKS; st += 32) {
        const size_t row = (size_t)(b * SS + s0 + st + r) * DMODEL + h * DHEAD + c8;
        const uint4 ku = *(const uint4*)(Kb + row);  // 8 bf16
        const uint4 vu = *(const uint4*)(Vb + row);
        __syncthreads();
        const unsigned ka_[4] = {ku.x, ku.y, ku.z, ku.w};
        const unsigned va_[4] = {vu.x, vu.y, vu.z, vu.w};
#pragma unroll
        for (int e = 0; e < 4; ++e) {
            kk[r][c8 + 2 * e]     = __uint_as_float(ka_[e] << 16);
            kk[r][c8 + 2 * e + 1] = __uint_as_float(ka_[e] & 0xFFFF0000u);
            vv[r][c8 + 2 * e]     = __uint_as_float(va_[e] << 16);
            vv[r][c8 + 2 * e + 1] = __uint_as_float(va_[e] & 0xFFFF0000u);
        }
        __syncthreads();
#pragma unroll 8
        for (int rr = 0; rr < 32; ++rr) {
            float4 kr = *(const float4*)&kk[rr][d0];
            float4 vr = *(const float4*)&vv[rr][f0];
            float ka[4] = {kr.x, kr.y, kr.z, kr.w};
            float va[4] = {vr.x, vr.y, vr.z, vr.w};
#pragma unroll
            for (int i = 0; i < 4; ++i)
#pragma unroll
                for (int j = 0; j < 4; ++j)
                    acc[i][j] = fmaf(ka[i], va[j], acc[i][j]);
        }
        if (t < 64) {
#pragma unroll 8
            for (int rr = 0; rr < 32; ++rr) ks += kk[rr][t];
        }
    }

    float* kvp = kv + (size_t)bh * DHEAD * DHEAD;
#pragma unroll
    for (int i = 0; i < 4; ++i)
#pragma unroll
        for (int j = 0; j < 4; ++j)
            atomicAdd(&kvp[(d0 + i) * DHEAD + f0 + j], acc[i][j]);
    if (t < 64) atomicAdd(&ksum[bh * DHEAD + t], ks);
}

// ---------------------------------------------------------------------------
// attn = (q.kv)/(q.ksum+1e-6), LDS-tiled: block = 64 tokens, loop 16 heads.
// Stage kv[b,h] (64x64 fp32) + q-tile (64x64, bf16->fp32) in LDS; each thread
// computes a 4-token x 4-f microtile. Output bf16 for the w_o GEMM.
// ---------------------------------------------------------------------------
__global__ __launch_bounds__(256) void la_attn(
    const unsigned short* __restrict__ Q, const float* __restrict__ kv,
    const float* __restrict__ ksum, unsigned short* __restrict__ attn)
{
    __shared__ float kvs[64][68];
    __shared__ float qs[64][68];
    __shared__ float kss[64];
    const int t = threadIdx.x;
    const int t0 = blockIdx.x * 64;
    const int b = t0 / SS;          // 64 | SS, so one batch per block
    const int tok_g = t >> 4;       // 0..15 -> tokens tok_g*4..+3
    const int f_g = t & 15;         // f = f_g*4..+3

    for (int hh = 0; hh < NHEADS; ++hh) {
        __syncthreads(); // previous head's LDS reads complete
        const float* kvp = kv + (size_t)(b * NHEADS + hh) * DHEAD * DHEAD;
#pragma unroll
        for (int i = 0; i < 4; ++i) { // 1024 float4 / 256 threads
            const int idx = i * 256 + t;
            const int r = idx >> 4, c4 = (idx & 15) * 4;
            *(float4*)&kvs[r][c4] = *(const float4*)(kvp + r * 64 + c4);
        }
        if (t < 64) kss[t] = ksum[(b * NHEADS + hh) * DHEAD + t];
#pragma unroll
        for (int i = 0; i < 2; ++i) { // 512 uint4 (8 bf16) / 256 threads
            const int idx = i * 256 + t;
            const int r = idx >> 3, c8 = (idx & 7) * 8;
            const uint4 qu = *(const uint4*)(Q + (size_t)(t0 + r) * DMODEL + hh * 64 + c8);
            const unsigned a[4] = {qu.x, qu.y, qu.z, qu.w};
#pragma unroll
            for (int e = 0; e < 4; ++e) {
                qs[r][c8 + 2 * e]     = __uint_as_float(a[e] << 16);
                qs[r][c8 + 2 * e + 1] = __uint_as_float(a[e] & 0xFFFF0000u);
            }
        }
        __syncthreads();

        float acc[4][4];
        float den[4];
#pragma unroll
        for (int i = 0; i < 4; ++i) {
            den[i] = 0.f;
#pragma unroll
            for (int j = 0; j < 4; ++j) acc[i][j] = 0.f;
        }
#pragma unroll 8
        for (int d = 0; d < 64; ++d) {
            const float4 kvf = *(const float4*)&kvs[d][f_g * 4];
            const float ks = kss[d];
#pragma unroll
            for (int i = 0; i < 4; ++i) {
                const float qd = qs[tok_g * 4 + i][d];
                den[i]    = fmaf(qd, ks,    den[i]);
                acc[i][0] = fmaf(qd, kvf.x, acc[i][0]);
                acc[i][1] = fmaf(qd, kvf.y, acc[i][1]);
                acc[i][2] = fmaf(qd, kvf.z, acc[i][2]);
                acc[i][3] = fmaf(qd, kvf.w, acc[i][3]);
            }
        }
#pragma unroll
        for (int i = 0; i < 4; ++i) {
            const float rcp = 1.f / (den[i] + 1e-6f);
            ushort4 o;
            o.x = f2bf(acc[i][0] * rcp); o.y = f2bf(acc[i][1] * rcp);
            o.z = f2bf(acc[i][2] * rcp); o.w = f2bf(acc[i][3] * rcp);
            *(ushort4*)(attn + (size_t)(t0 + tok_g * 4 + i) * DMODEL + hh * 64 + f_g * 4) = o;
        }
    }
}

// sentinel: unmistakable marker if workspace is too small
__global__ void la_sentinel(float* out, int n) {
    int i = blockIdx.x * 256 + threadIdx.x;
    if (i < n) out[i] = 12345.0f;
}

// ---------------------------------------------------------------------------
extern "C" void kernel_launch(void* const* d_in, const int* in_sizes, int n_in,
                              void* d_out, int out_size, void* d_ws, size_t ws_size,
                              hipStream_t stream)
{
    const float* x     = (const float*)d_in[0];  // (B,S,1024)
    const float* w_qkv = (const float*)d_in[1];  // (1024,3072)
    const float* w_o   = (const float*)d_in[2];  // (1024,1024)
    float* out = (float*)d_out;

    // workspace layout (bytes) — total ~278 MB (< 353 MB proven available)
    char* p = (char*)d_ws;
    const size_t x_bf = (size_t)MTOK * DMODEL * 2;          // 67.1 MB each
    unsigned short* x_hi = (unsigned short*)p; p += x_bf;   // reused as attn out
    unsigned short* wqT = (unsigned short*)p; p += (size_t)3 * DMODEL * DMODEL * 2;
    unsigned short* woT = (unsigned short*)p; p += (size_t)DMODEL * DMODEL * 2;
    unsigned short* q_buf = (unsigned short*)p; p += x_bf;  // bf16 q/k/v
    unsigned short* k_buf = (unsigned short*)p; p += x_bf;
    unsigned short* v_buf = (unsigned short*)p; p += x_bf;
    float* kvb = (float*)p; p += (size_t)BB * NHEADS * DHEAD * DHEAD * 4;
    float* ksb = (float*)p; p += (size_t)BB * NHEADS * DHEAD * 4;

    if ((size_t)(p - (char*)d_ws) > ws_size) {
        la_sentinel<<<(MTOK * DMODEL + 255) / 256, 256, 0, stream>>>(out, MTOK * DMODEL);
        return;
    }

    hipMemsetAsync(kvb, 0,
                   (size_t)(BB * NHEADS * DHEAD * DHEAD + BB * NHEADS * DHEAD) * sizeof(float),
                   stream);

    // 0) casts
    cast_bf16<<<8192, 256, 0, stream>>>((const float4*)x, (ushort4*)x_hi,
                                        MTOK * DMODEL / 4);
    cast_T<<<dim3(3 * DMODEL / 32, DMODEL / 32), 256, 0, stream>>>(w_qkv, wqT,
                                                                   DMODEL, 3 * DMODEL);
    cast_T<<<dim3(DMODEL / 32, DMODEL / 32), 256, 0, stream>>>(w_o, woT,
                                                               DMODEL, DMODEL);

    // 1) qkv GEMM (elu+1 fused on q,k), bf16 outputs
    la_gemm<1><<<dim3(3 * DMODEL / 128, MTOK / 128), 256, 0, stream>>>(
        x_hi, wqT, nullptr, q_buf, k_buf, v_buf, 3 * DMODEL, DMODEL);

    // 2) kv / ksum reduction (bf16 in, fp32 out)
    la_kvsum<<<dim3(BB * NHEADS, KV_CHUNKS), 256, 0, stream>>>(k_buf, v_buf, kvb, ksb);

    // 3) attn -> bf16 (reuses x_hi; x is dead after qkv GEMM)
    la_attn<<<MTOK / 64, 256, 0, stream>>>(q_buf, kvb, ksb, x_hi);

    // 4) out = attn @ w_o (fp32 out)
    la_gemm<0><<<dim3(DMODEL / 128, MTOK / 128), 256, 0, stream>>>(
        x_hi, woT, out, nullptr, nullptr, nullptr, DMODEL, DMODEL);
}